// Round 12
// baseline (94.817 us; speedup 1.0000x reference)
//
#include <hip/hip_runtime.h>
#include <hip/hip_bf16.h>

// B=32, H=W=96, D=128, WS=6, SS=3.
// Pipeline:
//  k_tile3   : h (151 MB, read ONCE) -> 3x3-tile sums S3 bf16 [b][ry32][c32][d128] (8 MB, ws)
//  k_tok     : S3 -> window means (4 tiles each) -> token_proj (bf16 MFMA) -> tok f32 (8 MB, ws)
//  k_fuse_out: 32-token blocks, grid 1024, 256 thr; K-split bf16 W staging
//              (wl [128][68] = 17.4 KB, staged lo/hi per GEMM); raw [32][132]
//              overlays wl. LDS 25.5 KB -> 6 blocks/CU (vs round-11's 2).
// Window decomposition: reg (wy,wx) = tiles {2wy,2wy+1}x{2wx,2wx+1};
// shifted = tiles {2wy+1,2wy+2 &31}x{2wx+1,2wx+2 &31}.
// S3 b-stride = 131072 elements (32*32*128).

#define DEVFN static __device__ __forceinline__

typedef __attribute__((ext_vector_type(8))) short bf16x8;
typedef __attribute__((ext_vector_type(16))) float f32x16;

DEVFN float gelu_exact(float x) {
  return 0.5f * x * (1.0f + erff(x * 0.70710678118654752f));
}

DEVFN unsigned short f2bf(float f) {  // RNE f32 -> bf16 bits (finite inputs)
  unsigned int u = __float_as_uint(f);
  u = (u + 0x7FFFu + ((u >> 16) & 1u)) >> 16;
  return (unsigned short)u;
}

DEVFN float bf2f(unsigned short u) {
  return __uint_as_float((unsigned int)u << 16);
}

DEVFN void add4(float4& a, const float4 v) {
  a.x += v.x; a.y += v.y; a.z += v.z; a.w += v.w;
}
DEVFN void fma4(float4& a, const float4 v, float m) {
  a.x = fmaf(v.x, m, a.x); a.y = fmaf(v.y, m, a.y);
  a.z = fmaf(v.z, m, a.z); a.w = fmaf(v.w, m, a.w);
}

// ---------------- Kernel 1: 3x3-tile sums, bf16 output (unchanged) ----------
__global__ __launch_bounds__(512) void k_tile3(const float* __restrict__ h,
                                               unsigned short* __restrict__ S3) {
  const int b  = blockIdx.x >> 5;
  const int ry = blockIdx.x & 31;
  const int w    = threadIdx.x >> 6;
  const int lane = threadIdx.x & 63;
  const int half = lane >> 5;
  const int ch4  = (lane & 31) << 2;
  const float mlo = half ? 0.f : 1.f;
  const float mhi = 1.f - mlo;

  float4 acc[4];
  #pragma unroll
  for (int t = 0; t < 4; ++t) acc[t] = make_float4(0.f, 0.f, 0.f, 0.f);

  #pragma unroll
  for (int yy = 0; yy < 3; ++yy) {
    const float* rp =
        h + ((size_t)(b * 9216 + (3 * ry + yy) * 96 + 12 * w + half) * 128 + ch4);
    #pragma unroll
    for (int j = 0; j < 6; ++j) {        // col = 12w + 2j + half
      const float4 v = *reinterpret_cast<const float4*>(rp + j * 256);
      if (j == 0)      add4(acc[0], v);
      else if (j == 2) add4(acc[1], v);
      else if (j == 3) add4(acc[2], v);
      else if (j == 5) add4(acc[3], v);
      else if (j == 1) { fma4(acc[0], v, mlo); fma4(acc[1], v, mhi); }
      else             { fma4(acc[2], v, mlo); fma4(acc[3], v, mhi); }
    }
  }

  #pragma unroll
  for (int t = 0; t < 4; ++t) {
    float4 s = acc[t];
    s.x += __shfl_xor(s.x, 32, 64);
    s.y += __shfl_xor(s.y, 32, 64);
    s.z += __shfl_xor(s.z, 32, 64);
    s.w += __shfl_xor(s.w, 32, 64);
    if (half == 0) {
      short4 pk;
      pk.x = (short)f2bf(s.x); pk.y = (short)f2bf(s.y);
      pk.z = (short)f2bf(s.z); pk.w = (short)f2bf(s.w);
      *reinterpret_cast<short4*>(
          &S3[((size_t)(b * 32 + ry) * 32 + 4 * w + t) * 128 + ch4]) = pk;
    }
  }
}

// ---------------- MFMA helpers ----------------
// Full-W stage (k_tok, 512 thr): f32 [k][n] -> bf16 LDS [n][136-row].
DEVFN void stage_w_bf(unsigned short* __restrict__ wl,
                      const float* __restrict__ W, int tid) {
  #pragma unroll
  for (int p = 0; p < 4; ++p) {
    const int i = tid + p * 512;            // 0..2047: kpair x n4-chunk
    const int kp = i >> 5;                  // k pair index 0..63
    const int n4 = (i & 31) * 4;
    const float4 r0 = *reinterpret_cast<const float4*>(W + (size_t)(2 * kp) * 128 + n4);
    const float4 r1 = *reinterpret_cast<const float4*>(W + (size_t)(2 * kp + 1) * 128 + n4);
    const float a0[4] = {r0.x, r0.y, r0.z, r0.w};
    const float a1[4] = {r1.x, r1.y, r1.z, r1.w};
    #pragma unroll
    for (int j = 0; j < 4; ++j) {
      const unsigned int pk =
          (unsigned int)f2bf(a0[j]) | ((unsigned int)f2bf(a1[j]) << 16);
      *reinterpret_cast<unsigned int*>(&wl[(n4 + j) * 136 + 2 * kp]) = pk;
    }
  }
}

// Half-W stage (k_fuse_out, 256 thr): 64 k-rows (krow0..+63) -> bf16 [n][68].
DEVFN void stage_w_half(unsigned short* __restrict__ wl,
                        const float* __restrict__ W, int krow0, int tid) {
  #pragma unroll
  for (int p = 0; p < 4; ++p) {
    const int i = tid + p * 256;            // 0..1023: kpair(32) x n4(32)
    const int kp = i >> 5;                  // local k pair 0..31
    const int n4 = (i & 31) * 4;
    const float4 r0 = *reinterpret_cast<const float4*>(W + (size_t)(krow0 + 2 * kp) * 128 + n4);
    const float4 r1 = *reinterpret_cast<const float4*>(W + (size_t)(krow0 + 2 * kp + 1) * 128 + n4);
    const float a0[4] = {r0.x, r0.y, r0.z, r0.w};
    const float a1[4] = {r1.x, r1.y, r1.z, r1.w};
    #pragma unroll
    for (int j = 0; j < 4; ++j) {
      const unsigned int pk =
          (unsigned int)f2bf(a0[j]) | ((unsigned int)f2bf(a1[j]) << 16);
      *reinterpret_cast<unsigned int*>(&wl[(n4 + j) * 68 + 2 * kp]) = pk;
    }
  }
}

// 8-step (K=128) MFMA tile, stride-16 frags (k_tok).
DEVFN f32x16 mfma_tile(const unsigned short* __restrict__ xrow,
                       const unsigned short* __restrict__ wrow) {
  f32x16 acc;
  #pragma unroll
  for (int r = 0; r < 16; ++r) acc[r] = 0.f;
  #pragma unroll
  for (int kk = 0; kk < 8; ++kk) {
    const bf16x8 a = *reinterpret_cast<const bf16x8*>(xrow + kk * 16);
    const bf16x8 bb = *reinterpret_cast<const bf16x8*>(wrow + kk * 16);
    acc = __builtin_amdgcn_mfma_f32_32x32x16_bf16(a, bb, acc, 0, 0, 0);
  }
  return acc;
}

// 4-step (K=64 half) MFMA accumulate (k_fuse_out).
DEVFN void mfma_tile4(const unsigned short* __restrict__ xrow,
                      const unsigned short* __restrict__ wrow, f32x16& acc) {
  #pragma unroll
  for (int kk = 0; kk < 4; ++kk) {
    const bf16x8 a = *reinterpret_cast<const bf16x8*>(xrow + kk * 16);
    const bf16x8 bb = *reinterpret_cast<const bf16x8*>(wrow + kk * 16);
    acc = __builtin_amdgcn_mfma_f32_32x32x16_bf16(a, bb, acc, 0, 0, 0);
  }
}

// C/D layout (verified m74/m101): col = lane&31, row = (r&3)+8*(r>>2)+4*(l>>5).
DEVFN void write_raw(float* __restrict__ raw, const f32x16 acc,
                     int tg, int cg, int lane) {
  const int n  = cg * 32 + (lane & 31);
  const int mb = tg * 32 + 4 * (lane >> 5);
  #pragma unroll
  for (int r = 0; r < 16; ++r) {
    const int mm = mb + (r & 3) + 8 * (r >> 2);
    raw[mm * 132 + n] = acc[r];
  }
}

// ---------------- Kernel 2: window gather + token_proj (unchanged) ----------
__global__ __launch_bounds__(512) void k_tok(const unsigned short* __restrict__ S3,
    const float* __restrict__ Wt, const float* __restrict__ bt,
    const float* __restrict__ gt, const float* __restrict__ bgt,
    float* __restrict__ tok) {
  __shared__ __align__(16) unsigned short xs_bf[64 * 136];
  __shared__ __align__(16) unsigned short wl[128 * 136];
  float* raw = reinterpret_cast<float*>(wl);

  const int tid = threadIdx.x;
  const int t0 = blockIdx.x * 64;
  const int s  = t0 >> 13;               // token set (uniform per block)
  const int b  = (t0 >> 8) & 31;
  const int wyx = t0 & 255;

  const unsigned short* Sb = S3 + (size_t)b * 131072;   // b-stride 32*32*128
  #pragma unroll
  for (int p = 0; p < 2; ++p) {
    const int i = tid + p * 512;          // 64 tokens x 16 chunks of 8 ch
    const int tt = i >> 4, c8 = (i & 15) * 8;
    const int idx = wyx + tt;
    const int wy = idx >> 4, wx = idx & 15;
    int ry0, ry1, c0, c1;
    if (s == 0) { ry0 = 2 * wy;     ry1 = 2 * wy + 1;        c0 = 2 * wx;     c1 = 2 * wx + 1; }
    else        { ry0 = 2 * wy + 1; ry1 = (2 * wy + 2) & 31; c0 = 2 * wx + 1; c1 = (2 * wx + 2) & 31; }
    const bf16x8 v00 = *reinterpret_cast<const bf16x8*>(Sb + ((size_t)(ry0 * 32 + c0) * 128 + c8));
    const bf16x8 v01 = *reinterpret_cast<const bf16x8*>(Sb + ((size_t)(ry0 * 32 + c1) * 128 + c8));
    const bf16x8 v10 = *reinterpret_cast<const bf16x8*>(Sb + ((size_t)(ry1 * 32 + c0) * 128 + c8));
    const bf16x8 v11 = *reinterpret_cast<const bf16x8*>(Sb + ((size_t)(ry1 * 32 + c1) * 128 + c8));
    bf16x8 pk;
    #pragma unroll
    for (int j = 0; j < 8; ++j) {
      const float sum = bf2f((unsigned short)v00[j]) + bf2f((unsigned short)v01[j]) +
                        bf2f((unsigned short)v10[j]) + bf2f((unsigned short)v11[j]);
      pk[j] = (short)f2bf(sum * (1.f / 36.f));
    }
    *reinterpret_cast<bf16x8*>(&xs_bf[tt * 136 + c8]) = pk;
  }
  stage_w_bf(wl, Wt, tid);
  __syncthreads();

  const int lane = tid & 63;
  const int w = tid >> 6;
  const int tg = w >> 2, cg = w & 3;
  const unsigned short* xrow = &xs_bf[(tg * 32 + (lane & 31)) * 136 + 8 * (lane >> 5)];
  const unsigned short* wrow = &wl[(cg * 32 + (lane & 31)) * 136 + 8 * (lane >> 5)];

  const f32x16 acc = mfma_tile(xrow, wrow);
  __syncthreads();
  write_raw(raw, acc, tg, cg, lane);
  __syncthreads();

  // LN+GELU -> tok f32. 8 threads/token.
  {
    const int tt = tid >> 3, cb = tid & 7;
    float v[16];
    float s2 = 0.f, q = 0.f;
    #pragma unroll
    for (int i = 0; i < 4; ++i) {
      const int col = 4 * cb + 32 * i;
      const float4 rv = *reinterpret_cast<const float4*>(&raw[tt * 132 + col]);
      const float4 bv = *reinterpret_cast<const float4*>(bt + col);
      v[4 * i + 0] = rv.x + bv.x; v[4 * i + 1] = rv.y + bv.y;
      v[4 * i + 2] = rv.z + bv.z; v[4 * i + 3] = rv.w + bv.w;
    }
    #pragma unroll
    for (int e = 0; e < 16; ++e) { s2 += v[e]; q += v[e] * v[e]; }
    s2 += __shfl_xor(s2, 1, 8); q += __shfl_xor(q, 1, 8);
    s2 += __shfl_xor(s2, 2, 8); q += __shfl_xor(q, 2, 8);
    s2 += __shfl_xor(s2, 4, 8); q += __shfl_xor(q, 4, 8);
    const float mean = s2 * (1.f / 128.f);
    const float var  = q * (1.f / 128.f) - mean * mean;
    const float inv  = rsqrtf(var + 1e-5f);
    #pragma unroll
    for (int i = 0; i < 4; ++i) {
      const int col = 4 * cb + 32 * i;
      const float4 gv = *reinterpret_cast<const float4*>(gt + col);
      const float4 ev = *reinterpret_cast<const float4*>(bgt + col);
      float4 ov;
      ov.x = gelu_exact((v[4 * i + 0] - mean) * inv * gv.x + ev.x);
      ov.y = gelu_exact((v[4 * i + 1] - mean) * inv * gv.y + ev.y);
      ov.z = gelu_exact((v[4 * i + 2] - mean) * inv * gv.z + ev.z);
      ov.w = gelu_exact((v[4 * i + 3] - mean) * inv * gv.w + ev.w);
      *reinterpret_cast<float4*>(tok + (size_t)(t0 + tt) * 128 + col) = ov;
    }
  }
}

// -------- Kernel 3: fuse + out_proj, 32-token blocks, K-split staging --------
// grid = 32*32 (b, gy), 256 threads = 4 waves (cg = wave). Token t = gx.
__global__ __launch_bounds__(256, 6) void k_fuse_out(const float* __restrict__ tok,
    const float* __restrict__ Wf, const float* __restrict__ bfv,
    const float* __restrict__ gf, const float* __restrict__ bgf,
    const float* __restrict__ Wo, const float* __restrict__ bo,
    const float* __restrict__ go, const float* __restrict__ bgo,
    const float* __restrict__ mask, float* __restrict__ out) {
  __shared__ __align__(16) unsigned short xs_bf[32 * 136];   //  8704 B
  __shared__ __align__(16) unsigned short wl[128 * 68];      // 17408 B
  float* raw = reinterpret_cast<float*>(wl);                 // [32][132] f32

  const int tid = threadIdx.x;
  const int b  = blockIdx.x >> 5;
  const int gy = blockIdx.x & 31;
  const int lane = tid & 63;
  const int cg = tid >> 6;                 // wave = col group

  const int wy  = gy >> 1;
  const int wys = ((gy + 31) & 31) >> 1;
  const float* tokR = tok + (size_t)b * 32768 + (size_t)wy * 2048;
  const float* tokS = tok + 1048576 + (size_t)b * 32768 + (size_t)wys * 2048;

  // Phase 0: gather reg+sh -> bf16 xs ; stage Wf-lo.
  #pragma unroll
  for (int p = 0; p < 2; ++p) {
    const int i = tid + p * 256;          // 32 rows x 16 chunks of 8 cols
    const int t = i >> 4, c8 = (i & 15) * 8;
    const int wx  = t >> 1;
    const int wxs = ((t + 31) & 31) >> 1;
    const float* pr = tokR + (size_t)wx * 128 + c8;
    const float* ps = tokS + (size_t)wxs * 128 + c8;
    bf16x8 pk;
    #pragma unroll
    for (int j = 0; j < 8; ++j)
      pk[j] = (short)f2bf(pr[j] + ps[j]);
    *reinterpret_cast<bf16x8*>(&xs_bf[t * 136 + c8]) = pk;
  }
  stage_w_half(wl, Wf, 0, tid);
  __syncthreads();

  const unsigned short* xrow = &xs_bf[(lane & 31) * 136 + 8 * (lane >> 5)];
  const unsigned short* wrow = &wl[(cg * 32 + (lane & 31)) * 68 + 8 * (lane >> 5)];

  f32x16 acc;
  #pragma unroll
  for (int r = 0; r < 16; ++r) acc[r] = 0.f;

  // Phase 1: fuse GEMM (K-split).
  mfma_tile4(xrow, wrow, acc);            // k 0..63
  __syncthreads();
  stage_w_half(wl, Wf, 64, tid);
  __syncthreads();
  mfma_tile4(xrow + 64, wrow, acc);       // k 64..127
  __syncthreads();                        // wl reads done before raw write
  write_raw(raw, acc, 0, cg, lane);
  __syncthreads();

  // Phase 2: LN+GELU(ctx) -> bf16 back into xs_bf. 8 threads/token.
  {
    const int tt = tid >> 3, cb = tid & 7;
    float v[16];
    float s = 0.f, q = 0.f;
    #pragma unroll
    for (int i = 0; i < 4; ++i) {
      const int col = 4 * cb + 32 * i;
      const float4 rv = *reinterpret_cast<const float4*>(&raw[tt * 132 + col]);
      const float4 bv = *reinterpret_cast<const float4*>(bfv + col);
      v[4 * i + 0] = rv.x + bv.x; v[4 * i + 1] = rv.y + bv.y;
      v[4 * i + 2] = rv.z + bv.z; v[4 * i + 3] = rv.w + bv.w;
    }
    #pragma unroll
    for (int e = 0; e < 16; ++e) { s += v[e]; q += v[e] * v[e]; }
    s += __shfl_xor(s, 1, 8); q += __shfl_xor(q, 1, 8);
    s += __shfl_xor(s, 2, 8); q += __shfl_xor(q, 2, 8);
    s += __shfl_xor(s, 4, 8); q += __shfl_xor(q, 4, 8);
    const float mean = s * (1.f / 128.f);
    const float var  = q * (1.f / 128.f) - mean * mean;
    const float inv  = rsqrtf(var + 1e-5f);
    #pragma unroll
    for (int i = 0; i < 4; ++i) {
      const int col = 4 * cb + 32 * i;
      const float4 gv = *reinterpret_cast<const float4*>(gf + col);
      const float4 ev = *reinterpret_cast<const float4*>(bgf + col);
      short4 pk;
      pk.x = (short)f2bf(gelu_exact((v[4 * i + 0] - mean) * inv * gv.x + ev.x));
      pk.y = (short)f2bf(gelu_exact((v[4 * i + 1] - mean) * inv * gv.y + ev.y));
      pk.z = (short)f2bf(gelu_exact((v[4 * i + 2] - mean) * inv * gv.z + ev.z));
      pk.w = (short)f2bf(gelu_exact((v[4 * i + 3] - mean) * inv * gv.w + ev.w));
      *reinterpret_cast<short4*>(&xs_bf[tt * 136 + col]) = pk;
    }
  }
  __syncthreads();                        // ctx complete + raw fully read

  // Phase 3: out_proj GEMM (K-split).
  stage_w_half(wl, Wo, 0, tid);
  __syncthreads();
  #pragma unroll
  for (int r = 0; r < 16; ++r) acc[r] = 0.f;
  mfma_tile4(xrow, wrow, acc);
  __syncthreads();
  stage_w_half(wl, Wo, 64, tid);
  __syncthreads();
  mfma_tile4(xrow + 64, wrow, acc);
  __syncthreads();
  write_raw(raw, acc, 0, cg, lane);
  __syncthreads();

  // Phase 4: LN+GELU(out) + mask + 3x3 expand stores.
  {
    const int tt = tid >> 3, cb = tid & 7;
    float v[16];
    float s = 0.f, q = 0.f;
    #pragma unroll
    for (int i = 0; i < 4; ++i) {
      const int col = 4 * cb + 32 * i;
      const float4 rv = *reinterpret_cast<const float4*>(&raw[tt * 132 + col]);
      const float4 bv = *reinterpret_cast<const float4*>(bo + col);
      v[4 * i + 0] = rv.x + bv.x; v[4 * i + 1] = rv.y + bv.y;
      v[4 * i + 2] = rv.z + bv.z; v[4 * i + 3] = rv.w + bv.w;
    }
    #pragma unroll
    for (int e = 0; e < 16; ++e) { s += v[e]; q += v[e] * v[e]; }
    s += __shfl_xor(s, 1, 8); q += __shfl_xor(q, 1, 8);
    s += __shfl_xor(s, 2, 8); q += __shfl_xor(q, 2, 8);
    s += __shfl_xor(s, 4, 8); q += __shfl_xor(q, 4, 8);
    const float mean = s * (1.f / 128.f);
    const float var  = q * (1.f / 128.f) - mean * mean;
    const float inv  = rsqrtf(var + 1e-5f);
    #pragma unroll
    for (int i = 0; i < 4; ++i) {
      const int col = 4 * cb + 32 * i;
      const float4 gv = *reinterpret_cast<const float4*>(go + col);
      const float4 ev = *reinterpret_cast<const float4*>(bgo + col);
      v[4 * i + 0] = gelu_exact((v[4 * i + 0] - mean) * inv * gv.x + ev.x);
      v[4 * i + 1] = gelu_exact((v[4 * i + 1] - mean) * inv * gv.y + ev.y);
      v[4 * i + 2] = gelu_exact((v[4 * i + 2] - mean) * inv * gv.z + ev.z);
      v[4 * i + 3] = gelu_exact((v[4 * i + 3] - mean) * inv * gv.w + ev.w);
    }
    const int gx = tt;
    #pragma unroll
    for (int py = 0; py < 3; ++py) {
      const int y = 3 * gy + py;
      #pragma unroll
      for (int px = 0; px < 3; ++px) {
        const int x = 3 * gx + px;
        const size_t pix = (size_t)b * 9216 + (size_t)y * 96 + x;
        const float mv = mask[pix];
        #pragma unroll
        for (int i = 0; i < 4; ++i) {
          const int col = 4 * cb + 32 * i;
          *reinterpret_cast<float4*>(out + pix * 128 + col) =
              make_float4(v[4 * i + 0] * mv, v[4 * i + 1] * mv,
                          v[4 * i + 2] * mv, v[4 * i + 3] * mv);
        }
      }
    }
  }
}

extern "C" void kernel_launch(void* const* d_in, const int* in_sizes, int n_in,
                              void* d_out, int out_size, void* d_ws, size_t ws_size,
                              hipStream_t stream) {
  (void)in_sizes; (void)n_in; (void)out_size; (void)ws_size;
  const float* h    = (const float*)d_in[0];
  const float* mask = (const float*)d_in[1];
  const float* Wt   = (const float*)d_in[2];
  const float* bt   = (const float*)d_in[3];
  const float* gt   = (const float*)d_in[4];
  const float* bgt  = (const float*)d_in[5];
  const float* Wf   = (const float*)d_in[6];
  const float* bfv  = (const float*)d_in[7];
  const float* gf   = (const float*)d_in[8];
  const float* bgf  = (const float*)d_in[9];
  const float* Wo   = (const float*)d_in[10];
  const float* bo   = (const float*)d_in[11];
  const float* go   = (const float*)d_in[12];
  const float* bgo  = (const float*)d_in[13];

  unsigned short* S3 = (unsigned short*)d_ws;                    // 8 MB
  float* tok = (float*)((char*)d_ws + (size_t)8 * 1024 * 1024);  // 8 MB
  float* out = (float*)d_out;

  hipLaunchKernelGGL(k_tile3, dim3(1024), dim3(512), 0, stream, h, S3);
  hipLaunchKernelGGL(k_tok, dim3(256), dim3(512), 0, stream,
                     S3, Wt, bt, gt, bgt, tok);
  hipLaunchKernelGGL(k_fuse_out, dim3(1024), dim3(256), 0, stream,
                     tok, Wf, bfv, gf, bgf, Wo, bo, go, bgo, mask, out);
}